// Round 1
// baseline (544.187 us; speedup 1.0000x reference)
//
#include <hip/hip_runtime.h>
#include <stdint.h>

#define SEQ 4096
#define DIMK 2048
#define HD 256

typedef __attribute__((ext_vector_type(8))) short bf16x8;
typedef __attribute__((ext_vector_type(4))) float f32x4;
typedef unsigned short u16;
typedef unsigned int u32;

__device__ __forceinline__ u16 f2bf(float f) {
    u32 u = __float_as_uint(f);
    u += 0x7FFFu + ((u >> 16) & 1u);   // round-to-nearest-even
    return (u16)(u >> 16);
}

// ---------------------------------------------------------------------------
// QKV projection: C[S,H] = X[S,D] @ W[H,D]^T + b   (bf16 out; q scaled)
// BM=64, BN=256 (full head), BK=64. 256 thr = 4 waves; wave w owns cols w*64..+63.
// LDS rows padded to 72 elems (144B): 16B-aligned b128 frag reads, 2-way banks.
// ---------------------------------------------------------------------------
__global__ __launch_bounds__(256) void qkv_gemm(
    const float* __restrict__ x,
    const float* __restrict__ Wq, const float* __restrict__ bq,
    const float* __restrict__ Wk, const float* __restrict__ bk,
    const float* __restrict__ Wv, const float* __restrict__ bv,
    u16* __restrict__ qb, u16* __restrict__ kb, u16* __restrict__ vb)
{
    const int z = blockIdx.y;
    const float* W    = (z == 0) ? Wq : (z == 1) ? Wk : Wv;
    const float* bias = (z == 0) ? bq : (z == 1) ? bk : bv;
    u16* outp         = (z == 0) ? qb : (z == 1) ? kb : vb;
    const float scale = (z == 0) ? 0.02209708691207961f : 1.0f;  // 1/sqrt(2048)

    __shared__ u16 As[64][72];
    __shared__ u16 Bs[HD][72];

    const int tid  = threadIdx.x;
    const int lane = tid & 63;
    const int w    = tid >> 6;
    const int r    = lane & 15, g = lane >> 4;
    const int m0   = blockIdx.x * 64;

    f32x4 zero = {0.f, 0.f, 0.f, 0.f};
    f32x4 acc[4][4];
    #pragma unroll
    for (int m = 0; m < 4; ++m)
        #pragma unroll
        for (int n = 0; n < 4; ++n) acc[m][n] = zero;

    for (int kt = 0; kt < DIMK / 64; ++kt) {
        // ---- stage A (64x64 f32 -> bf16) ----
        #pragma unroll
        for (int it = 0; it < 2; ++it) {
            int ch = it * 256 + tid;             // 512 chunks of 8
            int row = ch >> 3, colc = (ch & 7) * 8;
            const float* src = x + (size_t)(m0 + row) * DIMK + kt * 64 + colc;
            f32x4 a0 = *(const f32x4*)src;
            f32x4 a1 = *(const f32x4*)(src + 4);
            bf16x8 v8;
            v8[0]=(short)f2bf(a0[0]); v8[1]=(short)f2bf(a0[1]);
            v8[2]=(short)f2bf(a0[2]); v8[3]=(short)f2bf(a0[3]);
            v8[4]=(short)f2bf(a1[0]); v8[5]=(short)f2bf(a1[1]);
            v8[6]=(short)f2bf(a1[2]); v8[7]=(short)f2bf(a1[3]);
            *(bf16x8*)&As[row][colc] = v8;
        }
        // ---- stage B = W tile (256x64) ----
        #pragma unroll
        for (int it = 0; it < 8; ++it) {
            int ch = it * 256 + tid;             // 2048 chunks of 8
            int row = ch >> 3, colc = (ch & 7) * 8;
            const float* src = W + (size_t)row * DIMK + kt * 64 + colc;
            f32x4 a0 = *(const f32x4*)src;
            f32x4 a1 = *(const f32x4*)(src + 4);
            bf16x8 v8;
            v8[0]=(short)f2bf(a0[0]); v8[1]=(short)f2bf(a0[1]);
            v8[2]=(short)f2bf(a0[2]); v8[3]=(short)f2bf(a0[3]);
            v8[4]=(short)f2bf(a1[0]); v8[5]=(short)f2bf(a1[1]);
            v8[6]=(short)f2bf(a1[2]); v8[7]=(short)f2bf(a1[3]);
            *(bf16x8*)&Bs[row][colc] = v8;
        }
        __syncthreads();
        #pragma unroll
        for (int kc = 0; kc < 2; ++kc) {
            bf16x8 af[4], bfr[4];
            #pragma unroll
            for (int m = 0; m < 4; ++m)
                af[m] = *(const bf16x8*)&As[m*16 + r][kc*32 + g*8];
            #pragma unroll
            for (int n = 0; n < 4; ++n)
                bfr[n] = *(const bf16x8*)&Bs[w*64 + n*16 + r][kc*32 + g*8];
            #pragma unroll
            for (int m = 0; m < 4; ++m)
                #pragma unroll
                for (int n = 0; n < 4; ++n)
                    acc[m][n] = __builtin_amdgcn_mfma_f32_16x16x32_bf16(
                        af[m], bfr[n], acc[m][n], 0, 0, 0);
        }
        __syncthreads();
    }
    // ---- epilogue: +bias, scale, store bf16 ----
    #pragma unroll
    for (int n = 0; n < 4; ++n) {
        int col = w*64 + n*16 + r;
        float bcol = bias[col];
        #pragma unroll
        for (int m = 0; m < 4; ++m) {
            int row0 = m0 + m*16 + g*4;
            #pragma unroll
            for (int j = 0; j < 4; ++j) {
                float v = (acc[m][n][j] + bcol) * scale;
                outp[(size_t)(row0 + j) * HD + col] = f2bf(v);
            }
        }
    }
}

// ---------------------------------------------------------------------------
// Flash attention, causal. QBLK=64 (wave w: rows w*16..+15), KVBLK=64.
// Ks: [kv][256] bf16, 16B-slot swizzle  slot ^= (kv&7)          (32KB)
// Vt: [hd][64]  bf16 (transposed), slot ^= (hd&7)^((hd>>3)&7)   (32KB)
// Ps: per-wave [16][64] bf16 aliased into Ks, slot ^= (q&7)
// ---------------------------------------------------------------------------
__global__ __launch_bounds__(256) void attn_fwd(
    const u16* __restrict__ qb, const u16* __restrict__ kb,
    const u16* __restrict__ vb, float* __restrict__ out)
{
    __shared__ char Ks[64 * 512];
    __shared__ char Vt[256 * 128];

    const int tid  = threadIdx.x;
    const int lane = tid & 63;
    const int w    = tid >> 6;
    const int r    = lane & 15, g = lane >> 4;
    const int qt   = blockIdx.x;
    const float LOG2E = 1.4426950408889634f;

    char* Ps = Ks + w * 2048;

    // Q fragments (A-layout), 8 K-chunks of 32
    bf16x8 qf[8];
    {
        const u16* qp = qb + (size_t)(qt*64 + w*16 + r) * HD + g*8;
        #pragma unroll
        for (int c = 0; c < 8; ++c) qf[c] = *(const bf16x8*)(qp + c*32);
    }

    f32x4 zero = {0.f, 0.f, 0.f, 0.f};
    f32x4 o[16];
    #pragma unroll
    for (int i = 0; i < 16; ++i) o[i] = zero;
    float mrun[4], lrun[4];
    #pragma unroll
    for (int j = 0; j < 4; ++j) { mrun[j] = -__builtin_inff(); lrun[j] = 0.f; }

    const int qrow_l = w*16 + g*4;

    for (int t = 0; t <= qt; ++t) {
        __syncthreads();   // all waves done with Ks/Vt/Ps of previous tile
        // ---- stage K tile ----
        #pragma unroll
        for (int it = 0; it < 8; ++it) {
            int ch = it*256 + tid;               // 2048 chunks of 8
            int row = ch >> 5, colc = (ch & 31) * 8;
            bf16x8 k8 = *(const bf16x8*)(kb + (size_t)(t*64 + row)*HD + colc);
            int slot = (colc >> 3) ^ (row & 7);
            *(bf16x8*)(Ks + row*512 + slot*16) = k8;
        }
        // ---- stage V tile transposed (8x8 register transpose per thread) ----
        {
            int ht = tid & 31;                   // hd block = ht*8
            int vt = tid >> 5;                   // kv block = vt*8
            bf16x8 vin[8];
            #pragma unroll
            for (int i = 0; i < 8; ++i)
                vin[i] = *(const bf16x8*)(vb + (size_t)(t*64 + vt*8 + i)*HD + ht*8);
            #pragma unroll
            for (int j = 0; j < 8; ++j) {
                bf16x8 vo;
                #pragma unroll
                for (int i = 0; i < 8; ++i) vo[i] = vin[i][j];
                int hd = ht*8 + j;
                int slot = vt ^ (hd & 7) ^ ((hd >> 3) & 7);
                *(bf16x8*)(Vt + hd*128 + slot*16) = vo;
            }
        }
        __syncthreads();

        // ---- S = Q K^T (4 col-fragments over kv) ----
        f32x4 s[4];
        #pragma unroll
        for (int f = 0; f < 4; ++f) {
            s[f] = zero;
            int kv = f*16 + r;
            #pragma unroll
            for (int c = 0; c < 8; ++c) {
                int slot = (c*4 + g) ^ (kv & 7);
                bf16x8 kf = *(const bf16x8*)(Ks + kv*512 + slot*16);
                s[f] = __builtin_amdgcn_mfma_f32_16x16x32_bf16(qf[c], kf, s[f], 0, 0, 0);
            }
        }
        // ---- causal mask + online softmax ----
        #pragma unroll
        for (int j = 0; j < 4; ++j) {
            int qg = qt*64 + qrow_l + j;
            #pragma unroll
            for (int f = 0; f < 4; ++f) {
                int kvg = t*64 + f*16 + r;
                if (kvg > qg) s[f][j] = -__builtin_inff();
            }
            float mx = fmaxf(fmaxf(s[0][j], s[1][j]), fmaxf(s[2][j], s[3][j]));
            mx = fmaxf(mx, __shfl_xor(mx, 1));
            mx = fmaxf(mx, __shfl_xor(mx, 2));
            mx = fmaxf(mx, __shfl_xor(mx, 4));
            mx = fmaxf(mx, __shfl_xor(mx, 8));
            float mnew  = fmaxf(mrun[j], mx);
            float alpha = exp2f((mrun[j] - mnew) * LOG2E);
            mrun[j] = mnew;
            float rs = 0.f;
            #pragma unroll
            for (int f = 0; f < 4; ++f) {
                float p = exp2f((s[f][j] - mnew) * LOG2E);
                s[f][j] = p;
                rs += p;
            }
            rs += __shfl_xor(rs, 1); rs += __shfl_xor(rs, 2);
            rs += __shfl_xor(rs, 4); rs += __shfl_xor(rs, 8);
            lrun[j] = lrun[j] * alpha + rs;
            #pragma unroll
            for (int hf = 0; hf < 16; ++hf) o[hf][j] *= alpha;
        }
        __syncthreads();   // all waves finished reading Ks before P overwrites it

        // ---- write P (bf16) to per-wave Ps, D-layout -> swizzled rows ----
        #pragma unroll
        for (int f = 0; f < 4; ++f) {
            #pragma unroll
            for (int j = 0; j < 4; ++j) {
                int q  = g*4 + j;
                int kv = f*16 + r;
                int byte_off = (kv*2) ^ ((q & 7) << 4);
                *(u16*)(Ps + q*128 + byte_off) = f2bf(s[f][j]);
            }
        }
        // ---- read P as A-fragments ----
        bf16x8 pa[2];
        #pragma unroll
        for (int ck = 0; ck < 2; ++ck) {
            int slot = (ck*4 + g) ^ (r & 7);
            pa[ck] = *(const bf16x8*)(Ps + r*128 + slot*16);
        }
        // ---- O += P V ----
        #pragma unroll
        for (int hf = 0; hf < 16; ++hf) {
            int hd = hf*16 + r;
            #pragma unroll
            for (int ck = 0; ck < 2; ++ck) {
                int slot = (ck*4 + g) ^ (hd & 7) ^ ((hd >> 3) & 7);
                bf16x8 vf = *(const bf16x8*)(Vt + hd*128 + slot*16);
                o[hf] = __builtin_amdgcn_mfma_f32_16x16x32_bf16(pa[ck], vf, o[hf], 0, 0, 0);
            }
        }
    }

    // ---- epilogue: normalize and store f32 ----
    #pragma unroll
    for (int j = 0; j < 4; ++j) {
        float inv = 1.0f / lrun[j];
        int qg = qt*64 + qrow_l + j;
        float* op = out + (size_t)qg * HD;
        #pragma unroll
        for (int hf = 0; hf < 16; ++hf) op[hf*16 + r] = o[hf][j] * inv;
    }
}

extern "C" void kernel_launch(void* const* d_in, const int* in_sizes, int n_in,
                              void* d_out, int out_size, void* d_ws, size_t ws_size,
                              hipStream_t stream) {
    const float* x  = (const float*)d_in[0];
    const float* Wq = (const float*)d_in[1];
    const float* bq = (const float*)d_in[2];
    const float* Wk = (const float*)d_in[3];
    const float* bk = (const float*)d_in[4];
    const float* Wv = (const float*)d_in[5];
    const float* bv = (const float*)d_in[6];
    float* out = (float*)d_out;

    u16* qbuf = (u16*)d_ws;                         // 2 MB
    u16* kbuf = qbuf + (size_t)SEQ * HD;            // 2 MB
    u16* vbuf = kbuf + (size_t)SEQ * HD;            // 2 MB

    qkv_gemm<<<dim3(SEQ/64, 3), 256, 0, stream>>>(x, Wq, bq, Wk, bk, Wv, bv,
                                                  qbuf, kbuf, vbuf);
    attn_fwd<<<SEQ/64, 256, 0, stream>>>(qbuf, kbuf, vbuf, out);
}

// Round 2
// 108.227 us; speedup vs baseline: 5.0282x; 5.0282x over previous
//
#include <hip/hip_runtime.h>
#include <stdint.h>

#define SEQ 4096
#define DIMK 2048
#define HD 256

typedef __attribute__((ext_vector_type(8))) short bf16x8;
typedef __attribute__((ext_vector_type(4))) float f32x4;
typedef unsigned short u16;
typedef unsigned int u32;

__device__ __forceinline__ u16 f2bf(float f) {
    u32 u = __float_as_uint(f);
    u += 0x7FFFu + ((u >> 16) & 1u);   // round-to-nearest-even
    return (u16)(u >> 16);
}

__device__ __forceinline__ bf16x8 pack8(f32x4 a0, f32x4 a1) {
    bf16x8 v8;
    v8[0]=(short)f2bf(a0[0]); v8[1]=(short)f2bf(a0[1]);
    v8[2]=(short)f2bf(a0[2]); v8[3]=(short)f2bf(a0[3]);
    v8[4]=(short)f2bf(a1[0]); v8[5]=(short)f2bf(a1[1]);
    v8[6]=(short)f2bf(a1[2]); v8[7]=(short)f2bf(a1[3]);
    return v8;
}

// ---------------------------------------------------------------------------
// f32 -> bf16 bulk convert (grid-stride over 8-elem chunks)
// ---------------------------------------------------------------------------
__global__ __launch_bounds__(256) void f32_to_bf16(
    const float* __restrict__ src, u16* __restrict__ dst, int n8)
{
    int i = blockIdx.x * 256 + threadIdx.x;
    int stride = gridDim.x * 256;
    for (; i < n8; i += stride) {
        f32x4 a0 = *(const f32x4*)(src + (size_t)i*8);
        f32x4 a1 = *(const f32x4*)(src + (size_t)i*8 + 4);
        *(bf16x8*)(dst + (size_t)i*8) = pack8(a0, a1);
    }
}

// ---------------------------------------------------------------------------
// QKV projection from bf16: C[S,768] = xb[S,D] @ wb[768,D]^T + b
// BM=64, BN=128, BK=64. 4 waves; wave (wr,wc) owns 32x64 quadrant.
// LDS rows 128B with 16B-slot XOR swizzle (slot ^= row&7).
// ---------------------------------------------------------------------------
__global__ __launch_bounds__(256) void qkv_gemm_bf16(
    const u16* __restrict__ xb, const u16* __restrict__ wb,
    const float* __restrict__ bq, const float* __restrict__ bk,
    const float* __restrict__ bv,
    u16* __restrict__ qb, u16* __restrict__ kb, u16* __restrict__ vb)
{
    __shared__ char As[64*128];
    __shared__ char Bs[128*128];

    const int tid  = threadIdx.x;
    const int lane = tid & 63;
    const int w    = tid >> 6;
    const int r    = lane & 15, g = lane >> 4;
    const int wr   = w >> 1, wc = w & 1;
    const int m0   = blockIdx.x * 64;
    const int n0   = blockIdx.y * 128;
    const int z    = blockIdx.y >> 1;
    const float* bias = (z==0) ? bq : (z==1) ? bk : bv;
    u16* outp         = (z==0) ? qb : (z==1) ? kb : vb;
    const float scale = (z==0) ? 0.02209708691207961f : 1.0f;  // 1/sqrt(2048)

    f32x4 zero = {0.f,0.f,0.f,0.f};
    f32x4 acc[2][4];
    #pragma unroll
    for (int m = 0; m < 2; ++m)
        #pragma unroll
        for (int n = 0; n < 4; ++n) acc[m][n] = zero;

    for (int kt = 0; kt < DIMK/64; ++kt) {
        #pragma unroll
        for (int it = 0; it < 2; ++it) {
            int ch = it*256 + tid;
            int row = ch >> 3, slot = ch & 7;
            bf16x8 v8 = *(const bf16x8*)(xb + (size_t)(m0+row)*DIMK + kt*64 + slot*8);
            *(bf16x8*)(As + row*128 + ((slot ^ (row&7)) << 4)) = v8;
        }
        #pragma unroll
        for (int it = 0; it < 4; ++it) {
            int ch = it*256 + tid;
            int row = ch >> 3, slot = ch & 7;
            bf16x8 v8 = *(const bf16x8*)(wb + (size_t)(n0+row)*DIMK + kt*64 + slot*8);
            *(bf16x8*)(Bs + row*128 + ((slot ^ (row&7)) << 4)) = v8;
        }
        __syncthreads();
        #pragma unroll
        for (int kc = 0; kc < 2; ++kc) {
            bf16x8 af[2], bfr[4];
            #pragma unroll
            for (int m = 0; m < 2; ++m) {
                int arow = wr*32 + m*16 + r;
                af[m] = *(const bf16x8*)(As + arow*128 + (((kc*4+g) ^ (arow&7)) << 4));
            }
            #pragma unroll
            for (int n = 0; n < 4; ++n) {
                int brow = wc*64 + n*16 + r;
                bfr[n] = *(const bf16x8*)(Bs + brow*128 + (((kc*4+g) ^ (brow&7)) << 4));
            }
            #pragma unroll
            for (int m = 0; m < 2; ++m)
                #pragma unroll
                for (int n = 0; n < 4; ++n)
                    acc[m][n] = __builtin_amdgcn_mfma_f32_16x16x32_bf16(
                        af[m], bfr[n], acc[m][n], 0, 0, 0);
        }
        __syncthreads();
    }
    #pragma unroll
    for (int n = 0; n < 4; ++n) {
        int col = n0 + wc*64 + n*16 + r;
        int hc  = col & 255;
        float bcol = bias[hc];
        #pragma unroll
        for (int m = 0; m < 2; ++m) {
            int row0 = m0 + wr*32 + m*16 + g*4;
            #pragma unroll
            for (int j = 0; j < 4; ++j) {
                float v = (acc[m][n][j] + bcol) * scale;
                outp[(size_t)(row0+j)*HD + hc] = f2bf(v);
            }
        }
    }
}

// ---------------------------------------------------------------------------
// Split-KV flash attention partial. Block (qt, s): kv tiles [s*C, min(s*C+C,qt+1)).
// Writes unnormalized o + running (m,l) per q-row to partial buffers.
// ---------------------------------------------------------------------------
__global__ __launch_bounds__(256) void attn_part(
    const u16* __restrict__ qb, const u16* __restrict__ kb,
    const u16* __restrict__ vb,
    float* __restrict__ po, float* __restrict__ pm, float* __restrict__ pl,
    int C)
{
    const int qt = blockIdx.x;
    const int s  = blockIdx.y;
    if (s * C > qt) return;
    const int t0 = s * C;
    const int t1 = min(s*C + C, qt + 1);
    const int a  = qt / C, bres = qt - a*C;
    const int pid = C*a*(a+1)/2 + bres*(a+1) + s;

    __shared__ char Ks[64 * 512];
    __shared__ char Vt[256 * 128];

    const int tid  = threadIdx.x;
    const int lane = tid & 63;
    const int w    = tid >> 6;
    const int r    = lane & 15, g = lane >> 4;
    const float LOG2E = 1.4426950408889634f;

    char* Ps = Ks + w * 2048;

    bf16x8 qf[8];
    {
        const u16* qp = qb + (size_t)(qt*64 + w*16 + r) * HD + g*8;
        #pragma unroll
        for (int c = 0; c < 8; ++c) qf[c] = *(const bf16x8*)(qp + c*32);
    }

    f32x4 zero = {0.f,0.f,0.f,0.f};
    f32x4 o[16];
    #pragma unroll
    for (int i = 0; i < 16; ++i) o[i] = zero;
    float mrun[4], lrun[4];
    #pragma unroll
    for (int j = 0; j < 4; ++j) { mrun[j] = -__builtin_inff(); lrun[j] = 0.f; }

    const int qrow_l = w*16 + g*4;

    for (int t = t0; t < t1; ++t) {
        __syncthreads();
        #pragma unroll
        for (int it = 0; it < 8; ++it) {
            int ch = it*256 + tid;
            int row = ch >> 5, colc = (ch & 31) * 8;
            bf16x8 k8 = *(const bf16x8*)(kb + (size_t)(t*64 + row)*HD + colc);
            int slot = (colc >> 3) ^ (row & 7);
            *(bf16x8*)(Ks + row*512 + slot*16) = k8;
        }
        {
            int ht = tid & 31;
            int vt = tid >> 5;
            bf16x8 vin[8];
            #pragma unroll
            for (int i = 0; i < 8; ++i)
                vin[i] = *(const bf16x8*)(vb + (size_t)(t*64 + vt*8 + i)*HD + ht*8);
            #pragma unroll
            for (int j = 0; j < 8; ++j) {
                bf16x8 vo;
                #pragma unroll
                for (int i = 0; i < 8; ++i) vo[i] = vin[i][j];
                int hd = ht*8 + j;
                int slot = vt ^ (hd & 7) ^ ((hd >> 3) & 7);
                *(bf16x8*)(Vt + hd*128 + slot*16) = vo;
            }
        }
        __syncthreads();

        f32x4 sfr[4];
        #pragma unroll
        for (int f = 0; f < 4; ++f) {
            sfr[f] = zero;
            int kv = f*16 + r;
            #pragma unroll
            for (int c = 0; c < 8; ++c) {
                int slot = (c*4 + g) ^ (kv & 7);
                bf16x8 kf = *(const bf16x8*)(Ks + kv*512 + slot*16);
                sfr[f] = __builtin_amdgcn_mfma_f32_16x16x32_bf16(qf[c], kf, sfr[f], 0, 0, 0);
            }
        }
        #pragma unroll
        for (int j = 0; j < 4; ++j) {
            int qg = qt*64 + qrow_l + j;
            #pragma unroll
            for (int f = 0; f < 4; ++f) {
                int kvg = t*64 + f*16 + r;
                if (kvg > qg) sfr[f][j] = -__builtin_inff();
            }
            float mx = fmaxf(fmaxf(sfr[0][j], sfr[1][j]), fmaxf(sfr[2][j], sfr[3][j]));
            mx = fmaxf(mx, __shfl_xor(mx, 1));
            mx = fmaxf(mx, __shfl_xor(mx, 2));
            mx = fmaxf(mx, __shfl_xor(mx, 4));
            mx = fmaxf(mx, __shfl_xor(mx, 8));
            float mnew  = fmaxf(mrun[j], mx);
            float alpha = exp2f((mrun[j] - mnew) * LOG2E);
            mrun[j] = mnew;
            float rs = 0.f;
            #pragma unroll
            for (int f = 0; f < 4; ++f) {
                float p = exp2f((sfr[f][j] - mnew) * LOG2E);
                sfr[f][j] = p;
                rs += p;
            }
            rs += __shfl_xor(rs, 1); rs += __shfl_xor(rs, 2);
            rs += __shfl_xor(rs, 4); rs += __shfl_xor(rs, 8);
            lrun[j] = lrun[j] * alpha + rs;
            #pragma unroll
            for (int hf = 0; hf < 16; ++hf) o[hf][j] *= alpha;
        }
        __syncthreads();

        #pragma unroll
        for (int f = 0; f < 4; ++f) {
            #pragma unroll
            for (int j = 0; j < 4; ++j) {
                int q  = g*4 + j;
                int kv = f*16 + r;
                int byte_off = (kv*2) ^ ((q & 7) << 4);
                *(u16*)(Ps + q*128 + byte_off) = f2bf(sfr[f][j]);
            }
        }
        bf16x8 pa[2];
        #pragma unroll
        for (int ck = 0; ck < 2; ++ck) {
            int slot = (ck*4 + g) ^ (r & 7);
            pa[ck] = *(const bf16x8*)(Ps + r*128 + slot*16);
        }
        #pragma unroll
        for (int hf = 0; hf < 16; ++hf) {
            int hd = hf*16 + r;
            #pragma unroll
            for (int ck = 0; ck < 2; ++ck) {
                int slot = (ck*4 + g) ^ (hd & 7) ^ ((hd >> 3) & 7);
                bf16x8 vf = *(const bf16x8*)(Vt + hd*128 + slot*16);
                o[hf] = __builtin_amdgcn_mfma_f32_16x16x32_bf16(pa[ck], vf, o[hf], 0, 0, 0);
            }
        }
    }

    #pragma unroll
    for (int j = 0; j < 4; ++j) {
        int row_l = qrow_l + j;
        if (r == 0) {
            pm[(size_t)pid*64 + row_l] = mrun[j];
            pl[(size_t)pid*64 + row_l] = lrun[j];
        }
        float* op = po + ((size_t)pid*64 + row_l) * 256;
        #pragma unroll
        for (int hf = 0; hf < 16; ++hf) op[hf*16 + r] = o[hf][j];
    }
}

// ---------------------------------------------------------------------------
// Combine split partials: out = sum_s e^(m_s-M) o_s / sum_s e^(m_s-M) l_s
// ---------------------------------------------------------------------------
__global__ __launch_bounds__(256) void attn_combine(
    const float* __restrict__ po, const float* __restrict__ pm,
    const float* __restrict__ pl, float* __restrict__ out, int C)
{
    const float LOG2E = 1.4426950408889634f;
    const int tid = threadIdx.x;
    const int row = blockIdx.x * 16 + (tid >> 4);
    const int cg  = tid & 15;
    const int qt  = row >> 6;
    const int rr  = row & 63;
    const int ns  = qt / C + 1;
    const int a   = qt / C, bres = qt - a*C;
    const int pid0 = C*a*(a+1)/2 + bres*(a+1);

    float M = -__builtin_inff();
    for (int s = 0; s < ns; ++s)
        M = fmaxf(M, pm[(size_t)(pid0+s)*64 + rr]);

    float lt = 0.f;
    f32x4 acc[4];
    f32x4 zero = {0.f,0.f,0.f,0.f};
    #pragma unroll
    for (int i = 0; i < 4; ++i) acc[i] = zero;

    for (int s = 0; s < ns; ++s) {
        float ms = pm[(size_t)(pid0+s)*64 + rr];
        float wgt = exp2f((ms - M) * LOG2E);
        lt += wgt * pl[(size_t)(pid0+s)*64 + rr];
        const f32x4* p = (const f32x4*)(po + ((size_t)(pid0+s)*64 + rr)*256 + cg*16);
        #pragma unroll
        for (int i = 0; i < 4; ++i) acc[i] += p[i] * wgt;
    }
    float inv = 1.f / lt;
    f32x4* op = (f32x4*)(out + (size_t)row*256 + cg*16);
    #pragma unroll
    for (int i = 0; i < 4; ++i) op[i] = acc[i] * inv;
}

// ===========================================================================
// Fallback (round-0 verified kernels) — used only if ws_size is too small.
// ===========================================================================
__global__ __launch_bounds__(256) void qkv_gemm_f32(
    const float* __restrict__ x,
    const float* __restrict__ Wq, const float* __restrict__ bq,
    const float* __restrict__ Wk, const float* __restrict__ bk,
    const float* __restrict__ Wv, const float* __restrict__ bv,
    u16* __restrict__ qb, u16* __restrict__ kb, u16* __restrict__ vb)
{
    const int z = blockIdx.y;
    const float* W    = (z == 0) ? Wq : (z == 1) ? Wk : Wv;
    const float* bias = (z == 0) ? bq : (z == 1) ? bk : bv;
    u16* outp         = (z == 0) ? qb : (z == 1) ? kb : vb;
    const float scale = (z == 0) ? 0.02209708691207961f : 1.0f;

    __shared__ u16 As[64][72];
    __shared__ u16 Bs[HD][72];

    const int tid  = threadIdx.x;
    const int lane = tid & 63;
    const int w    = tid >> 6;
    const int r    = lane & 15, g = lane >> 4;
    const int m0   = blockIdx.x * 64;

    f32x4 zero = {0.f,0.f,0.f,0.f};
    f32x4 acc[4][4];
    #pragma unroll
    for (int m = 0; m < 4; ++m)
        #pragma unroll
        for (int n = 0; n < 4; ++n) acc[m][n] = zero;

    for (int kt = 0; kt < DIMK / 64; ++kt) {
        #pragma unroll
        for (int it = 0; it < 2; ++it) {
            int ch = it * 256 + tid;
            int row = ch >> 3, colc = (ch & 7) * 8;
            const float* src = x + (size_t)(m0 + row) * DIMK + kt * 64 + colc;
            *(bf16x8*)&As[row][colc] = pack8(*(const f32x4*)src, *(const f32x4*)(src+4));
        }
        #pragma unroll
        for (int it = 0; it < 8; ++it) {
            int ch = it * 256 + tid;
            int row = ch >> 3, colc = (ch & 7) * 8;
            const float* src = W + (size_t)row * DIMK + kt * 64 + colc;
            *(bf16x8*)&Bs[row][colc] = pack8(*(const f32x4*)src, *(const f32x4*)(src+4));
        }
        __syncthreads();
        #pragma unroll
        for (int kc = 0; kc < 2; ++kc) {
            bf16x8 af[4], bfr[4];
            #pragma unroll
            for (int m = 0; m < 4; ++m)
                af[m] = *(const bf16x8*)&As[m*16 + r][kc*32 + g*8];
            #pragma unroll
            for (int n = 0; n < 4; ++n)
                bfr[n] = *(const bf16x8*)&Bs[w*64 + n*16 + r][kc*32 + g*8];
            #pragma unroll
            for (int m = 0; m < 4; ++m)
                #pragma unroll
                for (int n = 0; n < 4; ++n)
                    acc[m][n] = __builtin_amdgcn_mfma_f32_16x16x32_bf16(
                        af[m], bfr[n], acc[m][n], 0, 0, 0);
        }
        __syncthreads();
    }
    #pragma unroll
    for (int n = 0; n < 4; ++n) {
        int col = w*64 + n*16 + r;
        float bcol = bias[col];
        #pragma unroll
        for (int m = 0; m < 4; ++m) {
            int row0 = m0 + m*16 + g*4;
            #pragma unroll
            for (int j = 0; j < 4; ++j) {
                float v = (acc[m][n][j] + bcol) * scale;
                outp[(size_t)(row0 + j) * HD + col] = f2bf(v);
            }
        }
    }
}

__global__ __launch_bounds__(256) void attn_fused(
    const u16* __restrict__ qb, const u16* __restrict__ kb,
    const u16* __restrict__ vb, float* __restrict__ out)
{
    __shared__ char Ks[64 * 512];
    __shared__ char Vt[256 * 128];

    const int tid  = threadIdx.x;
    const int lane = tid & 63;
    const int w    = tid >> 6;
    const int r    = lane & 15, g = lane >> 4;
    const int qt   = blockIdx.x;
    const float LOG2E = 1.4426950408889634f;

    char* Ps = Ks + w * 2048;

    bf16x8 qf[8];
    {
        const u16* qp = qb + (size_t)(qt*64 + w*16 + r) * HD + g*8;
        #pragma unroll
        for (int c = 0; c < 8; ++c) qf[c] = *(const bf16x8*)(qp + c*32);
    }

    f32x4 zero = {0.f,0.f,0.f,0.f};
    f32x4 o[16];
    #pragma unroll
    for (int i = 0; i < 16; ++i) o[i] = zero;
    float mrun[4], lrun[4];
    #pragma unroll
    for (int j = 0; j < 4; ++j) { mrun[j] = -__builtin_inff(); lrun[j] = 0.f; }

    const int qrow_l = w*16 + g*4;

    for (int t = 0; t <= qt; ++t) {
        __syncthreads();
        #pragma unroll
        for (int it = 0; it < 8; ++it) {
            int ch = it*256 + tid;
            int row = ch >> 5, colc = (ch & 31) * 8;
            bf16x8 k8 = *(const bf16x8*)(kb + (size_t)(t*64 + row)*HD + colc);
            int slot = (colc >> 3) ^ (row & 7);
            *(bf16x8*)(Ks + row*512 + slot*16) = k8;
        }
        {
            int ht = tid & 31;
            int vt = tid >> 5;
            bf16x8 vin[8];
            #pragma unroll
            for (int i = 0; i < 8; ++i)
                vin[i] = *(const bf16x8*)(vb + (size_t)(t*64 + vt*8 + i)*HD + ht*8);
            #pragma unroll
            for (int j = 0; j < 8; ++j) {
                bf16x8 vo;
                #pragma unroll
                for (int i = 0; i < 8; ++i) vo[i] = vin[i][j];
                int hd = ht*8 + j;
                int slot = vt ^ (hd & 7) ^ ((hd >> 3) & 7);
                *(bf16x8*)(Vt + hd*128 + slot*16) = vo;
            }
        }
        __syncthreads();

        f32x4 sfr[4];
        #pragma unroll
        for (int f = 0; f < 4; ++f) {
            sfr[f] = zero;
            int kv = f*16 + r;
            #pragma unroll
            for (int c = 0; c < 8; ++c) {
                int slot = (c*4 + g) ^ (kv & 7);
                bf16x8 kf = *(const bf16x8*)(Ks + kv*512 + slot*16);
                sfr[f] = __builtin_amdgcn_mfma_f32_16x16x32_bf16(qf[c], kf, sfr[f], 0, 0, 0);
            }
        }
        #pragma unroll
        for (int j = 0; j < 4; ++j) {
            int qg = qt*64 + qrow_l + j;
            #pragma unroll
            for (int f = 0; f < 4; ++f) {
                int kvg = t*64 + f*16 + r;
                if (kvg > qg) sfr[f][j] = -__builtin_inff();
            }
            float mx = fmaxf(fmaxf(sfr[0][j], sfr[1][j]), fmaxf(sfr[2][j], sfr[3][j]));
            mx = fmaxf(mx, __shfl_xor(mx, 1));
            mx = fmaxf(mx, __shfl_xor(mx, 2));
            mx = fmaxf(mx, __shfl_xor(mx, 4));
            mx = fmaxf(mx, __shfl_xor(mx, 8));
            float mnew  = fmaxf(mrun[j], mx);
            float alpha = exp2f((mrun[j] - mnew) * LOG2E);
            mrun[j] = mnew;
            float rs = 0.f;
            #pragma unroll
            for (int f = 0; f < 4; ++f) {
                float p = exp2f((sfr[f][j] - mnew) * LOG2E);
                sfr[f][j] = p;
                rs += p;
            }
            rs += __shfl_xor(rs, 1); rs += __shfl_xor(rs, 2);
            rs += __shfl_xor(rs, 4); rs += __shfl_xor(rs, 8);
            lrun[j] = lrun[j] * alpha + rs;
            #pragma unroll
            for (int hf = 0; hf < 16; ++hf) o[hf][j] *= alpha;
        }
        __syncthreads();

        #pragma unroll
        for (int f = 0; f < 4; ++f) {
            #pragma unroll
            for (int j = 0; j < 4; ++j) {
                int q  = g*4 + j;
                int kv = f*16 + r;
                int byte_off = (kv*2) ^ ((q & 7) << 4);
                *(u16*)(Ps + q*128 + byte_off) = f2bf(sfr[f][j]);
            }
        }
        bf16x8 pa[2];
        #pragma unroll
        for (int ck = 0; ck < 2; ++ck) {
            int slot = (ck*4 + g) ^ (r & 7);
            pa[ck] = *(const bf16x8*)(Ps + r*128 + slot*16);
        }
        #pragma unroll
        for (int hf = 0; hf < 16; ++hf) {
            int hd = hf*16 + r;
            #pragma unroll
            for (int ck = 0; ck < 2; ++ck) {
                int slot = (ck*4 + g) ^ (hd & 7) ^ ((hd >> 3) & 7);
                bf16x8 vf = *(const bf16x8*)(Vt + hd*128 + slot*16);
                o[hf] = __builtin_amdgcn_mfma_f32_16x16x32_bf16(pa[ck], vf, o[hf], 0, 0, 0);
            }
        }
    }

    #pragma unroll
    for (int j = 0; j < 4; ++j) {
        float inv = 1.0f / lrun[j];
        int qg = qt*64 + qrow_l + j;
        float* op = out + (size_t)qg * HD;
        #pragma unroll
        for (int hf = 0; hf < 16; ++hf) op[hf*16 + r] = o[hf][j] * inv;
    }
}

extern "C" void kernel_launch(void* const* d_in, const int* in_sizes, int n_in,
                              void* d_out, int out_size, void* d_ws, size_t ws_size,
                              hipStream_t stream) {
    const float* x  = (const float*)d_in[0];
    const float* Wq = (const float*)d_in[1];
    const float* bq = (const float*)d_in[2];
    const float* Wk = (const float*)d_in[3];
    const float* bk = (const float*)d_in[4];
    const float* Wv = (const float*)d_in[5];
    const float* bv = (const float*)d_in[6];
    float* out = (float*)d_out;

    const size_t xb_bytes = (size_t)SEQ * DIMK * 2;      // 16 MB
    const size_t wb_bytes = (size_t)768 * DIMK * 2;      // 3 MB
    const size_t qkv_bytes = (size_t)SEQ * HD * 2;       // 2 MB each
    const size_t base = xb_bytes + wb_bytes + 3 * qkv_bytes;

    // pick split chunk C (kv tiles per block): prefer smallest that fits
    int C = 0; size_t npid = 0;
    const int cand[4] = {4, 8, 16, 64};
    for (int i = 0; i < 4; ++i) {
        int c = cand[i];
        int a = 64 / c;
        size_t np = (size_t)c * a * (a+1) / 2;
        if (base + np * (65536 + 512) <= ws_size) { C = c; npid = np; break; }
    }

    if (C == 0) {
        // fallback: round-0 path (needs only 6 MB of ws)
        u16* qbuf = (u16*)d_ws;
        u16* kbuf = qbuf + (size_t)SEQ * HD;
        u16* vbuf = kbuf + (size_t)SEQ * HD;
        qkv_gemm_f32<<<dim3(SEQ/64, 3), 256, 0, stream>>>(
            x, Wq, bq, Wk, bk, Wv, bv, qbuf, kbuf, vbuf);
        attn_fused<<<SEQ/64, 256, 0, stream>>>(qbuf, kbuf, vbuf, out);
        return;
    }

    char* p = (char*)d_ws;
    u16* xb   = (u16*)p; p += xb_bytes;
    u16* wb   = (u16*)p; p += wb_bytes;
    u16* qbuf = (u16*)p; p += qkv_bytes;
    u16* kbuf = (u16*)p; p += qkv_bytes;
    u16* vbuf = (u16*)p; p += qkv_bytes;
    float* po = (float*)p; p += npid * 65536;
    float* pm = (float*)p; p += npid * 256;
    float* pl = (float*)p; p += npid * 256;

    f32_to_bf16<<<4096, 256, 0, stream>>>(x, xb, SEQ*DIMK/8);
    f32_to_bf16<<<256, 256, 0, stream>>>(Wq, wb,            HD*DIMK/8);
    f32_to_bf16<<<256, 256, 0, stream>>>(Wk, wb + HD*DIMK,  HD*DIMK/8);
    f32_to_bf16<<<256, 256, 0, stream>>>(Wv, wb + 2*HD*DIMK, HD*DIMK/8);

    qkv_gemm_bf16<<<dim3(SEQ/64, 6), 256, 0, stream>>>(
        xb, wb, bq, bk, bv, qbuf, kbuf, vbuf);

    attn_part<<<dim3(64, 64 / C), 256, 0, stream>>>(
        qbuf, kbuf, vbuf, po, pm, pl, C);

    attn_combine<<<256, 256, 0, stream>>>(po, pm, pl, out, C);
}

// Round 3
// 106.214 us; speedup vs baseline: 5.1235x; 1.0190x over previous
//
#include <hip/hip_runtime.h>
#include <stdint.h>

#define SEQ 4096
#define DIMK 2048
#define HD 256

typedef __attribute__((ext_vector_type(8))) short bf16x8;
typedef __attribute__((ext_vector_type(4))) float f32x4;
typedef unsigned short u16;
typedef unsigned int u32;

__device__ __forceinline__ u16 f2bf(float f) {
    u32 u = __float_as_uint(f);
    u += 0x7FFFu + ((u >> 16) & 1u);   // round-to-nearest-even
    return (u16)(u >> 16);
}

__device__ __forceinline__ bf16x8 pack8(f32x4 a0, f32x4 a1) {
    bf16x8 v8;
    v8[0]=(short)f2bf(a0[0]); v8[1]=(short)f2bf(a0[1]);
    v8[2]=(short)f2bf(a0[2]); v8[3]=(short)f2bf(a0[3]);
    v8[4]=(short)f2bf(a1[0]); v8[5]=(short)f2bf(a1[1]);
    v8[6]=(short)f2bf(a1[2]); v8[7]=(short)f2bf(a1[3]);
    return v8;
}

// ---------------------------------------------------------------------------
// f32 -> bf16 bulk convert, all 4 tensors in one launch (y: 0=x, 1..3=W)
// ---------------------------------------------------------------------------
__global__ __launch_bounds__(256) void cvt_all(
    const float* __restrict__ x, const float* __restrict__ Wq,
    const float* __restrict__ Wk, const float* __restrict__ Wv,
    u16* __restrict__ xb, u16* __restrict__ wb)
{
    const int y = blockIdx.y;
    const float* src; u16* dst; int n8;
    if (y == 0)      { src = x;  dst = xb;                 n8 = SEQ*DIMK/8; }
    else if (y == 1) { src = Wq; dst = wb;                 n8 = HD*DIMK/8; }
    else if (y == 2) { src = Wk; dst = wb + HD*DIMK;       n8 = HD*DIMK/8; }
    else             { src = Wv; dst = wb + 2*HD*DIMK;     n8 = HD*DIMK/8; }
    int i = blockIdx.x * 256 + threadIdx.x;
    int stride = gridDim.x * 256;
    for (; i < n8; i += stride) {
        f32x4 a0 = *(const f32x4*)(src + (size_t)i*8);
        f32x4 a1 = *(const f32x4*)(src + (size_t)i*8 + 4);
        *(bf16x8*)(dst + (size_t)i*8) = pack8(a0, a1);
    }
}

// ---------------------------------------------------------------------------
// QKV projection from bf16: C[S,768] = xb[S,D] @ wb[768,D]^T + b  (verified)
// ---------------------------------------------------------------------------
__global__ __launch_bounds__(256) void qkv_gemm_bf16(
    const u16* __restrict__ xb, const u16* __restrict__ wb,
    const float* __restrict__ bq, const float* __restrict__ bk,
    const float* __restrict__ bv,
    u16* __restrict__ qb, u16* __restrict__ kb, u16* __restrict__ vb)
{
    __shared__ char As[64*128];
    __shared__ char Bs[128*128];

    const int tid  = threadIdx.x;
    const int lane = tid & 63;
    const int w    = tid >> 6;
    const int r    = lane & 15, g = lane >> 4;
    const int wr   = w >> 1, wc = w & 1;
    const int m0   = blockIdx.x * 64;
    const int n0   = blockIdx.y * 128;
    const int z    = blockIdx.y >> 1;
    const float* bias = (z==0) ? bq : (z==1) ? bk : bv;
    u16* outp         = (z==0) ? qb : (z==1) ? kb : vb;
    const float scale = (z==0) ? 0.02209708691207961f : 1.0f;  // 1/sqrt(2048)

    f32x4 zero = {0.f,0.f,0.f,0.f};
    f32x4 acc[2][4];
    #pragma unroll
    for (int m = 0; m < 2; ++m)
        #pragma unroll
        for (int n = 0; n < 4; ++n) acc[m][n] = zero;

    for (int kt = 0; kt < DIMK/64; ++kt) {
        #pragma unroll
        for (int it = 0; it < 2; ++it) {
            int ch = it*256 + tid;
            int row = ch >> 3, slot = ch & 7;
            bf16x8 v8 = *(const bf16x8*)(xb + (size_t)(m0+row)*DIMK + kt*64 + slot*8);
            *(bf16x8*)(As + row*128 + ((slot ^ (row&7)) << 4)) = v8;
        }
        #pragma unroll
        for (int it = 0; it < 4; ++it) {
            int ch = it*256 + tid;
            int row = ch >> 3, slot = ch & 7;
            bf16x8 v8 = *(const bf16x8*)(wb + (size_t)(n0+row)*DIMK + kt*64 + slot*8);
            *(bf16x8*)(Bs + row*128 + ((slot ^ (row&7)) << 4)) = v8;
        }
        __syncthreads();
        #pragma unroll
        for (int kc = 0; kc < 2; ++kc) {
            bf16x8 af[2], bfr[4];
            #pragma unroll
            for (int m = 0; m < 2; ++m) {
                int arow = wr*32 + m*16 + r;
                af[m] = *(const bf16x8*)(As + arow*128 + (((kc*4+g) ^ (arow&7)) << 4));
            }
            #pragma unroll
            for (int n = 0; n < 4; ++n) {
                int brow = wc*64 + n*16 + r;
                bfr[n] = *(const bf16x8*)(Bs + brow*128 + (((kc*4+g) ^ (brow&7)) << 4));
            }
            #pragma unroll
            for (int m = 0; m < 2; ++m)
                #pragma unroll
                for (int n = 0; n < 4; ++n)
                    acc[m][n] = __builtin_amdgcn_mfma_f32_16x16x32_bf16(
                        af[m], bfr[n], acc[m][n], 0, 0, 0);
        }
        __syncthreads();
    }
    #pragma unroll
    for (int n = 0; n < 4; ++n) {
        int col = n0 + wc*64 + n*16 + r;
        int hc  = col & 255;
        float bcol = bias[hc];
        #pragma unroll
        for (int m = 0; m < 2; ++m) {
            int row0 = m0 + wr*32 + m*16 + g*4;
            #pragma unroll
            for (int j = 0; j < 4; ++j) {
                float v = (acc[m][n][j] + bcol) * scale;
                outp[(size_t)(row0+j)*HD + hc] = f2bf(v);
            }
        }
    }
}

// ---------------------------------------------------------------------------
// Split-KV flash attention partial, SWAPPED-operand form.
// S^T = mfma(K,Q): lane (r,g) holds S[q=r][kv=f*16+g*4+j]  -> lane-local softmax.
// O^T = mfma(Vt,P^T): lane (r,g) holds O[q=r][hd=hf*16+g*4+j].
// K/V prefetched into registers one tile ahead (T14). 2 barriers/tile.
// ---------------------------------------------------------------------------
__global__ __launch_bounds__(256) void attn_part(
    const u16* __restrict__ qb, const u16* __restrict__ kb,
    const u16* __restrict__ vb,
    float* __restrict__ po, float* __restrict__ pm, float* __restrict__ pl,
    int C)
{
    const int qt = blockIdx.x;
    const int s  = blockIdx.y;
    if (s * C > qt) return;
    const int t0 = s * C;
    const int t1 = min(s*C + C, qt + 1);
    const int a  = qt / C, bres = qt - a*C;
    const int pid = C*a*(a+1)/2 + bres*(a+1) + s;

    __shared__ char Ks[64 * 512];      // [kv][256 d] bf16, 16B-slot swz ^(kv&7)
    __shared__ char Vt[256 * 128];     // [hd][64 kv] bf16, swz ^(hd&7)^((hd>>3)&7)
    __shared__ char Ps[4 * 16 * 144];  // per-wave [q=16][64 kv] bf16, 144B pad rows

    const int tid  = threadIdx.x;
    const int lane = tid & 63;
    const int w    = tid >> 6;
    const int r    = lane & 15, g = lane >> 4;
    const float LOG2E = 1.4426950408889634f;

    char* Psw = Ps + w * (16*144);

    // Q B-frags: lane r = q-row (w*16+r), d-slice g*8 + c*32
    bf16x8 qf[8];
    {
        const u16* qp = qb + (size_t)(qt*64 + w*16 + r) * HD + g*8;
        #pragma unroll
        for (int c = 0; c < 8; ++c) qf[c] = *(const bf16x8*)(qp + c*32);
    }

    f32x4 zero = {0.f,0.f,0.f,0.f};
    f32x4 o[16];
    #pragma unroll
    for (int i = 0; i < 16; ++i) o[i] = zero;
    float mrun = -__builtin_inff(), lrun = 0.f;
    const int qg = qt*64 + w*16 + r;

    // staging roles
    const int krow = tid >> 5;           // + it*8
    const int kcol = (tid & 31) * 8;
    const int ht   = tid & 31;           // hd block ht*8
    const int vt   = tid >> 5;           // kv block vt*8

    bf16x8 kreg[8], vreg[8];
    {
        const u16* kp = kb + (size_t)(t0*64 + krow)*HD + kcol;
        #pragma unroll
        for (int it = 0; it < 8; ++it) kreg[it] = *(const bf16x8*)(kp + (size_t)it*8*HD);
        const u16* vp = vb + (size_t)(t0*64 + vt*8)*HD + ht*8;
        #pragma unroll
        for (int i = 0; i < 8; ++i) vreg[i] = *(const bf16x8*)(vp + (size_t)i*HD);
    }

    for (int t = t0; t < t1; ++t) {
        __syncthreads();   // everyone done reading Ks/Vt of previous tile
        // ---- ds_write K from regs ----
        #pragma unroll
        for (int it = 0; it < 8; ++it) {
            int row = krow + it*8;
            int slot = (kcol >> 3) ^ (row & 7);
            *(bf16x8*)(Ks + row*512 + slot*16) = kreg[it];
        }
        // ---- transpose V in regs + ds_write ----
        #pragma unroll
        for (int j = 0; j < 8; ++j) {
            bf16x8 vo;
            #pragma unroll
            for (int i = 0; i < 8; ++i) vo[i] = vreg[i][j];
            int hd = ht*8 + j;
            int slot = vt ^ (hd & 7) ^ ((hd >> 3) & 7);
            *(bf16x8*)(Vt + hd*128 + slot*16) = vo;
        }
        // ---- prefetch next tile into regs (hides under compute below) ----
        if (t + 1 < t1) {
            const u16* kp = kb + (size_t)((t+1)*64 + krow)*HD + kcol;
            #pragma unroll
            for (int it = 0; it < 8; ++it) kreg[it] = *(const bf16x8*)(kp + (size_t)it*8*HD);
            const u16* vp = vb + (size_t)((t+1)*64 + vt*8)*HD + ht*8;
            #pragma unroll
            for (int i = 0; i < 8; ++i) vreg[i] = *(const bf16x8*)(vp + (size_t)i*HD);
        }
        __syncthreads();

        // ---- S^T = K Q^T : sv[f][j] = S[q=r][kv = f*16 + g*4 + j] ----
        f32x4 sv[4];
        #pragma unroll
        for (int f = 0; f < 4; ++f) {
            sv[f] = zero;
            int kv = f*16 + r;
            #pragma unroll
            for (int c = 0; c < 8; ++c) {
                int slot = (c*4 + g) ^ (kv & 7);
                bf16x8 kf = *(const bf16x8*)(Ks + kv*512 + slot*16);
                sv[f] = __builtin_amdgcn_mfma_f32_16x16x32_bf16(kf, qf[c], sv[f], 0, 0, 0);
            }
        }
        // ---- causal mask (q = lane-scalar qg) ----
        #pragma unroll
        for (int f = 0; f < 4; ++f)
            #pragma unroll
            for (int j = 0; j < 4; ++j) {
                int kvg = t*64 + f*16 + g*4 + j;
                if (kvg > qg) sv[f][j] = -__builtin_inff();
            }
        // ---- lane-local online softmax (row = q = r) ----
        float mx = -__builtin_inff();
        #pragma unroll
        for (int f = 0; f < 4; ++f)
            #pragma unroll
            for (int j = 0; j < 4; ++j) mx = fmaxf(mx, sv[f][j]);
        mx = fmaxf(mx, __shfl_xor(mx, 16));
        mx = fmaxf(mx, __shfl_xor(mx, 32));
        float mnew  = fmaxf(mrun, mx);
        float alpha = exp2f((mrun - mnew) * LOG2E);
        mrun = mnew;
        float rs = 0.f;
        #pragma unroll
        for (int f = 0; f < 4; ++f)
            #pragma unroll
            for (int j = 0; j < 4; ++j) {
                float p = exp2f((sv[f][j] - mnew) * LOG2E);
                sv[f][j] = p;
                rs += p;
            }
        rs += __shfl_xor(rs, 16);
        rs += __shfl_xor(rs, 32);
        lrun = lrun * alpha + rs;
        #pragma unroll
        for (int hf = 0; hf < 16; ++hf) o[hf] *= alpha;

        // ---- P -> bf16 -> per-wave Ps (no barrier: wave-local) ----
        #pragma unroll
        for (int f = 0; f < 4; ++f)
            #pragma unroll
            for (int i = 0; i < 2; ++i) {
                u32 pk = (u32)f2bf(sv[f][2*i]) | ((u32)f2bf(sv[f][2*i+1]) << 16);
                *(u32*)(Psw + r*144 + (f*8 + g*2 + i)*4) = pk;
            }
        bf16x8 pa[2];
        #pragma unroll
        for (int ck = 0; ck < 2; ++ck)
            pa[ck] = *(const bf16x8*)(Psw + r*144 + ck*64 + g*16);

        // ---- O^T += V^T P^T ----
        #pragma unroll
        for (int hf = 0; hf < 16; ++hf) {
            int hd = hf*16 + r;
            #pragma unroll
            for (int ck = 0; ck < 2; ++ck) {
                int slot = (ck*4 + g) ^ (hd & 7) ^ ((hd >> 3) & 7);
                bf16x8 vf = *(const bf16x8*)(Vt + hd*128 + slot*16);
                o[hf] = __builtin_amdgcn_mfma_f32_16x16x32_bf16(vf, pa[ck], o[hf], 0, 0, 0);
            }
        }
    }

    // ---- epilogue: lane (r,g) holds O[q=r][hd=hf*16+g*4+j] ----
    if (g == 0) {
        pm[(size_t)pid*64 + w*16 + r] = mrun;
        pl[(size_t)pid*64 + w*16 + r] = lrun;
    }
    float* op = po + ((size_t)pid*64 + w*16 + r) * 256;
    #pragma unroll
    for (int hf = 0; hf < 16; ++hf)
        *(f32x4*)(op + hf*16 + g*4) = o[hf];
}

// ---------------------------------------------------------------------------
// Combine split partials: out = sum_s e^(m_s-M) o_s / sum_s e^(m_s-M) l_s
// ---------------------------------------------------------------------------
__global__ __launch_bounds__(256) void attn_combine(
    const float* __restrict__ po, const float* __restrict__ pm,
    const float* __restrict__ pl, float* __restrict__ out, int C)
{
    const float LOG2E = 1.4426950408889634f;
    const int tid = threadIdx.x;
    const int row = blockIdx.x * 16 + (tid >> 4);
    const int cg  = tid & 15;
    const int qt  = row >> 6;
    const int rr  = row & 63;
    const int ns  = qt / C + 1;
    const int a   = qt / C, bres = qt - a*C;
    const int pid0 = C*a*(a+1)/2 + bres*(a+1);

    float M = -__builtin_inff();
    for (int s = 0; s < ns; ++s)
        M = fmaxf(M, pm[(size_t)(pid0+s)*64 + rr]);

    float lt = 0.f;
    f32x4 acc[4];
    f32x4 zero = {0.f,0.f,0.f,0.f};
    #pragma unroll
    for (int i = 0; i < 4; ++i) acc[i] = zero;

    for (int s = 0; s < ns; ++s) {
        float ms = pm[(size_t)(pid0+s)*64 + rr];
        float wgt = exp2f((ms - M) * LOG2E);
        lt += wgt * pl[(size_t)(pid0+s)*64 + rr];
        const f32x4* p = (const f32x4*)(po + ((size_t)(pid0+s)*64 + rr)*256 + cg*16);
        #pragma unroll
        for (int i = 0; i < 4; ++i) acc[i] += p[i] * wgt;
    }
    float inv = 1.f / lt;
    f32x4* op = (f32x4*)(out + (size_t)row*256 + cg*16);
    #pragma unroll
    for (int i = 0; i < 4; ++i) op[i] = acc[i] * inv;
}

// ===========================================================================
// Fallback (round-0 verified kernels) — used only if ws_size is too small.
// ===========================================================================
__global__ __launch_bounds__(256) void qkv_gemm_f32(
    const float* __restrict__ x,
    const float* __restrict__ Wq, const float* __restrict__ bq,
    const float* __restrict__ Wk, const float* __restrict__ bk,
    const float* __restrict__ Wv, const float* __restrict__ bv,
    u16* __restrict__ qb, u16* __restrict__ kb, u16* __restrict__ vb)
{
    const int z = blockIdx.y;
    const float* W    = (z == 0) ? Wq : (z == 1) ? Wk : Wv;
    const float* bias = (z == 0) ? bq : (z == 1) ? bk : bv;
    u16* outp         = (z == 0) ? qb : (z == 1) ? kb : vb;
    const float scale = (z == 0) ? 0.02209708691207961f : 1.0f;

    __shared__ u16 As[64][72];
    __shared__ u16 Bs[HD][72];

    const int tid  = threadIdx.x;
    const int lane = tid & 63;
    const int w    = tid >> 6;
    const int r    = lane & 15, g = lane >> 4;
    const int m0   = blockIdx.x * 64;

    f32x4 zero = {0.f,0.f,0.f,0.f};
    f32x4 acc[4][4];
    #pragma unroll
    for (int m = 0; m < 4; ++m)
        #pragma unroll
        for (int n = 0; n < 4; ++n) acc[m][n] = zero;

    for (int kt = 0; kt < DIMK / 64; ++kt) {
        #pragma unroll
        for (int it = 0; it < 2; ++it) {
            int ch = it * 256 + tid;
            int row = ch >> 3, colc = (ch & 7) * 8;
            const float* src = x + (size_t)(m0 + row) * DIMK + kt * 64 + colc;
            *(bf16x8*)&As[row][colc] = pack8(*(const f32x4*)src, *(const f32x4*)(src+4));
        }
        #pragma unroll
        for (int it = 0; it < 8; ++it) {
            int ch = it * 256 + tid;
            int row = ch >> 3, colc = (ch & 7) * 8;
            const float* src = W + (size_t)row * DIMK + kt * 64 + colc;
            *(bf16x8*)&Bs[row][colc] = pack8(*(const f32x4*)src, *(const f32x4*)(src+4));
        }
        __syncthreads();
        #pragma unroll
        for (int kc = 0; kc < 2; ++kc) {
            bf16x8 af[4], bfr[4];
            #pragma unroll
            for (int m = 0; m < 4; ++m)
                af[m] = *(const bf16x8*)&As[m*16 + r][kc*32 + g*8];
            #pragma unroll
            for (int n = 0; n < 4; ++n)
                bfr[n] = *(const bf16x8*)&Bs[w*64 + n*16 + r][kc*32 + g*8];
            #pragma unroll
            for (int m = 0; m < 4; ++m)
                #pragma unroll
                for (int n = 0; n < 4; ++n)
                    acc[m][n] = __builtin_amdgcn_mfma_f32_16x16x32_bf16(
                        af[m], bfr[n], acc[m][n], 0, 0, 0);
        }
        __syncthreads();
    }
    #pragma unroll
    for (int n = 0; n < 4; ++n) {
        int col = w*64 + n*16 + r;
        float bcol = bias[col];
        #pragma unroll
        for (int m = 0; m < 4; ++m) {
            int row0 = m0 + m*16 + g*4;
            #pragma unroll
            for (int j = 0; j < 4; ++j) {
                float v = (acc[m][n][j] + bcol) * scale;
                outp[(size_t)(row0 + j) * HD + col] = f2bf(v);
            }
        }
    }
}

__global__ __launch_bounds__(256) void attn_fused(
    const u16* __restrict__ qb, const u16* __restrict__ kb,
    const u16* __restrict__ vb, float* __restrict__ out)
{
    __shared__ char Ks[64 * 512];
    __shared__ char Vt[256 * 128];

    const int tid  = threadIdx.x;
    const int lane = tid & 63;
    const int w    = tid >> 6;
    const int r    = lane & 15, g = lane >> 4;
    const int qt   = blockIdx.x;
    const float LOG2E = 1.4426950408889634f;

    char* Ps = Ks + w * 2048;

    bf16x8 qf[8];
    {
        const u16* qp = qb + (size_t)(qt*64 + w*16 + r) * HD + g*8;
        #pragma unroll
        for (int c = 0; c < 8; ++c) qf[c] = *(const bf16x8*)(qp + c*32);
    }

    f32x4 zero = {0.f,0.f,0.f,0.f};
    f32x4 o[16];
    #pragma unroll
    for (int i = 0; i < 16; ++i) o[i] = zero;
    float mrun[4], lrun[4];
    #pragma unroll
    for (int j = 0; j < 4; ++j) { mrun[j] = -__builtin_inff(); lrun[j] = 0.f; }

    const int qrow_l = w*16 + g*4;

    for (int t = 0; t <= qt; ++t) {
        __syncthreads();
        #pragma unroll
        for (int it = 0; it < 8; ++it) {
            int ch = it*256 + tid;
            int row = ch >> 5, colc = (ch & 31) * 8;
            bf16x8 k8 = *(const bf16x8*)(kb + (size_t)(t*64 + row)*HD + colc);
            int slot = (colc >> 3) ^ (row & 7);
            *(bf16x8*)(Ks + row*512 + slot*16) = k8;
        }
        {
            int ht = tid & 31;
            int vt = tid >> 5;
            bf16x8 vin[8];
            #pragma unroll
            for (int i = 0; i < 8; ++i)
                vin[i] = *(const bf16x8*)(vb + (size_t)(t*64 + vt*8 + i)*HD + ht*8);
            #pragma unroll
            for (int j = 0; j < 8; ++j) {
                bf16x8 vo;
                #pragma unroll
                for (int i = 0; i < 8; ++i) vo[i] = vin[i][j];
                int hd = ht*8 + j;
                int slot = vt ^ (hd & 7) ^ ((hd >> 3) & 7);
                *(bf16x8*)(Vt + hd*128 + slot*16) = vo;
            }
        }
        __syncthreads();

        f32x4 sfr[4];
        #pragma unroll
        for (int f = 0; f < 4; ++f) {
            sfr[f] = zero;
            int kv = f*16 + r;
            #pragma unroll
            for (int c = 0; c < 8; ++c) {
                int slot = (c*4 + g) ^ (kv & 7);
                bf16x8 kf = *(const bf16x8*)(Ks + kv*512 + slot*16);
                sfr[f] = __builtin_amdgcn_mfma_f32_16x16x32_bf16(qf[c], kf, sfr[f], 0, 0, 0);
            }
        }
        #pragma unroll
        for (int j = 0; j < 4; ++j) {
            int qg = qt*64 + qrow_l + j;
            #pragma unroll
            for (int f = 0; f < 4; ++f) {
                int kvg = t*64 + f*16 + r;
                if (kvg > qg) sfr[f][j] = -__builtin_inff();
            }
            float mx = fmaxf(fmaxf(sfr[0][j], sfr[1][j]), fmaxf(sfr[2][j], sfr[3][j]));
            mx = fmaxf(mx, __shfl_xor(mx, 1));
            mx = fmaxf(mx, __shfl_xor(mx, 2));
            mx = fmaxf(mx, __shfl_xor(mx, 4));
            mx = fmaxf(mx, __shfl_xor(mx, 8));
            float mnew  = fmaxf(mrun[j], mx);
            float alpha = exp2f((mrun[j] - mnew) * LOG2E);
            mrun[j] = mnew;
            float rs = 0.f;
            #pragma unroll
            for (int f = 0; f < 4; ++f) {
                float p = exp2f((sfr[f][j] - mnew) * LOG2E);
                sfr[f][j] = p;
                rs += p;
            }
            rs += __shfl_xor(rs, 1); rs += __shfl_xor(rs, 2);
            rs += __shfl_xor(rs, 4); rs += __shfl_xor(rs, 8);
            lrun[j] = lrun[j] * alpha + rs;
            #pragma unroll
            for (int hf = 0; hf < 16; ++hf) o[hf][j] *= alpha;
        }
        __syncthreads();

        #pragma unroll
        for (int f = 0; f < 4; ++f) {
            #pragma unroll
            for (int j = 0; j < 4; ++j) {
                int q  = g*4 + j;
                int kv = f*16 + r;
                int byte_off = (kv*2) ^ ((q & 7) << 4);
                *(u16*)(Ps + q*128 + byte_off) = f2bf(sfr[f][j]);
            }
        }
        bf16x8 pa[2];
        #pragma unroll
        for (int ck = 0; ck < 2; ++ck) {
            int slot = (ck*4 + g) ^ (r & 7);
            pa[ck] = *(const bf16x8*)(Ps + r*128 + slot*16);
        }
        #pragma unroll
        for (int hf = 0; hf < 16; ++hf) {
            int hd = hf*16 + r;
            #pragma unroll
            for (int ck = 0; ck < 2; ++ck) {
                int slot = (ck*4 + g) ^ (hd & 7) ^ ((hd >> 3) & 7);
                bf16x8 vf = *(const bf16x8*)(Vt + hd*128 + slot*16);
                o[hf] = __builtin_amdgcn_mfma_f32_16x16x32_bf16(pa[ck], vf, o[hf], 0, 0, 0);
            }
        }
    }

    #pragma unroll
    for (int j = 0; j < 4; ++j) {
        float inv = 1.0f / lrun[j];
        int qg = qt*64 + qrow_l + j;
        float* op = out + (size_t)qg * HD;
        #pragma unroll
        for (int hf = 0; hf < 16; ++hf) op[hf*16 + r] = o[hf][j] * inv;
    }
}

extern "C" void kernel_launch(void* const* d_in, const int* in_sizes, int n_in,
                              void* d_out, int out_size, void* d_ws, size_t ws_size,
                              hipStream_t stream) {
    const float* x  = (const float*)d_in[0];
    const float* Wq = (const float*)d_in[1];
    const float* bq = (const float*)d_in[2];
    const float* Wk = (const float*)d_in[3];
    const float* bk = (const float*)d_in[4];
    const float* Wv = (const float*)d_in[5];
    const float* bv = (const float*)d_in[6];
    float* out = (float*)d_out;

    const size_t xb_bytes = (size_t)SEQ * DIMK * 2;      // 16 MB
    const size_t wb_bytes = (size_t)768 * DIMK * 2;      // 3 MB
    const size_t qkv_bytes = (size_t)SEQ * HD * 2;       // 2 MB each
    const size_t base = xb_bytes + wb_bytes + 3 * qkv_bytes;

    int C = 0; size_t npid = 0;
    const int cand[4] = {4, 8, 16, 64};
    for (int i = 0; i < 4; ++i) {
        int c = cand[i];
        int a = 64 / c;
        size_t np = (size_t)c * a * (a+1) / 2;
        if (base + np * (65536 + 512) <= ws_size) { C = c; npid = np; break; }
    }

    if (C == 0) {
        u16* qbuf = (u16*)d_ws;
        u16* kbuf = qbuf + (size_t)SEQ * HD;
        u16* vbuf = kbuf + (size_t)SEQ * HD;
        qkv_gemm_f32<<<dim3(SEQ/64, 3), 256, 0, stream>>>(
            x, Wq, bq, Wk, bk, Wv, bv, qbuf, kbuf, vbuf);
        attn_fused<<<SEQ/64, 256, 0, stream>>>(qbuf, kbuf, vbuf, out);
        return;
    }

    char* p = (char*)d_ws;
    u16* xb   = (u16*)p; p += xb_bytes;
    u16* wb   = (u16*)p; p += wb_bytes;
    u16* qbuf = (u16*)p; p += qkv_bytes;
    u16* kbuf = (u16*)p; p += qkv_bytes;
    u16* vbuf = (u16*)p; p += qkv_bytes;
    float* po = (float*)p; p += npid * 65536;
    float* pm = (float*)p; p += npid * 256;
    float* pl = (float*)p; p += npid * 256;

    cvt_all<<<dim3(512, 4), 256, 0, stream>>>(x, Wq, Wk, Wv, xb, wb);

    qkv_gemm_bf16<<<dim3(SEQ/64, 6), 256, 0, stream>>>(
        xb, wb, bq, bk, bv, qbuf, kbuf, vbuf);

    attn_part<<<dim3(64, 64 / C), 256, 0, stream>>>(
        qbuf, kbuf, vbuf, po, pm, pl, C);

    attn_combine<<<256, 256, 0, stream>>>(po, pm, pl, out, C);
}